// Round 16
// baseline (224.251 us; speedup 1.0000x reference)
//
#include <hip/hip_runtime.h>
#include <cstdint>
#include <cstddef>

typedef float  f32x4  __attribute__((ext_vector_type(4)));
typedef short  bf16x8 __attribute__((ext_vector_type(8)));
typedef short  bf16x4 __attribute__((ext_vector_type(4)));

constexpr int Bc = 4, Lc = 1024, Dc = 1024, Kc = 8, Hc = 64, NHc = 512;
constexpr float SCALE = 0.125f;                       // 1/sqrt(64)
constexpr long long GSZ = 2LL * Bc * Kc * Lc * Lc;    // graphs elems (both layers)
constexpr long long OSZ = (long long)Bc * Lc * Dc;    // hidden elems per layer
constexpr int QB = 16;                                // q-rows per attn block

__device__ __forceinline__ unsigned short f2bf(float f) {
    unsigned u = __float_as_uint(f);
    u += 0x7fffu + ((u >> 16) & 1u);   // RNE
    return (unsigned short)(u >> 16);
}
__device__ __forceinline__ float bf2f(unsigned short s) {
    return __uint_as_float((unsigned)s << 16);
}

// ---------------------------------------------------------------------------
// cast fp32 -> bf16, 8 elems/thread
// ---------------------------------------------------------------------------
__global__ __launch_bounds__(256)
void cast_bf16(const float* __restrict__ in, unsigned short* __restrict__ outp, int n)
{
    const int i = (blockIdx.x * 256 + threadIdx.x) * 8;
    if (i >= n) return;
    float4 a = *(const float4*)(in + i);
    float4 b = *(const float4*)(in + i + 4);
    bf16x8 v;
    v[0] = (short)f2bf(a.x); v[1] = (short)f2bf(a.y);
    v[2] = (short)f2bf(a.z); v[3] = (short)f2bf(a.w);
    v[4] = (short)f2bf(b.x); v[5] = (short)f2bf(b.y);
    v[6] = (short)f2bf(b.z); v[7] = (short)f2bf(b.w);
    *(bf16x8*)(outp + i) = v;
}

// ---------------------------------------------------------------------------
// K0: W [1024 k][512 n] fp32 -> Wt [512 n][1024 k] bf16, parked in d_out att
// region (overwritten later by attn_fused). z: layer*2 + (0=q,1=k).
// ---------------------------------------------------------------------------
__global__ __launch_bounds__(256)
void wtrans(const float* __restrict__ Wq, const float* __restrict__ Wk,
            float* __restrict__ outbase)
{
    __shared__ float Tl[64][68];
    const int z = blockIdx.z, layer = z >> 1, m = z & 1;
    const float* src = (m ? Wk : Wq) + (size_t)layer * Dc * NHc;
    unsigned short* dst = (unsigned short*)(outbase + (size_t)layer * (GSZ / 2))
                          + (size_t)m * NHc * Dc;
    const int k0 = blockIdx.x * 64, n0 = blockIdx.y * 64;
    const int t = threadIdx.x;
    {
        const int r0 = t >> 4, c0 = (t & 15) * 4;
        #pragma unroll
        for (int i = 0; i < 4; ++i)
            *(float4*)&Tl[r0 + 16 * i][c0] =
                *(const float4*)&src[(size_t)(k0 + r0 + 16 * i) * NHc + n0 + c0];
    }
    __syncthreads();
    {
        const int nn = t >> 2, ks = (t & 3) * 16;
        bf16x8 v0, v1;
        #pragma unroll
        for (int j = 0; j < 8; ++j) v0[j] = (short)f2bf(Tl[ks + j][nn]);
        #pragma unroll
        for (int j = 0; j < 8; ++j) v1[j] = (short)f2bf(Tl[ks + 8 + j][nn]);
        unsigned short* dp = dst + (size_t)(n0 + nn) * Dc + k0 + ks;
        *(bf16x8*)dp       = v0;
        *(bf16x8*)(dp + 8) = v1;
    }
}

// ---------------------------------------------------------------------------
// K1: q/k projection GEMM, LDS-staged (coalesced global reads), double-buffered.
// Tile 128x128, BK=32, 512 thr = 8 waves, wave tile 64x32 (4x2 frags).
// ---------------------------------------------------------------------------
__global__ __launch_bounds__(512)
void qk_gemm(const unsigned short* __restrict__ hidb,
             const unsigned short* __restrict__ Wtq, const unsigned short* __restrict__ Wtk,
             const float* __restrict__ bq, const float* __restrict__ bk,
             unsigned short* __restrict__ qbuf, unsigned short* __restrict__ kbuf)
{
    __shared__ unsigned short As[2][128][40];
    __shared__ unsigned short Bs[2][128][40];

    const unsigned short* Wt = blockIdx.z ? Wtk : Wtq;
    const float* bi = blockIdx.z ? bk : bq;
    unsigned short* C = blockIdx.z ? kbuf : qbuf;
    const int m0 = blockIdx.x * 128, n0 = blockIdx.y * 128;
    const int t = threadIdx.x, lane = t & 63, w = t >> 6;
    const int lr = lane & 15, lg = lane >> 4;
    const int wmloc = (w >> 2) * 64, wnloc = (w & 3) * 32;

    const int srow = t >> 2, scol = (t & 3) * 8;
    const unsigned short* Ag = hidb + (size_t)(m0 + srow) * Dc + scol;
    const unsigned short* Bg = Wt   + (size_t)(n0 + srow) * Dc + scol;

    f32x4 acc[4][2] = {};
    bf16x8 ra = *(const bf16x8*)Ag;
    bf16x8 rb = *(const bf16x8*)Bg;

    for (int it = 0; it < 32; ++it) {
        const int buf = it & 1;
        *(bf16x8*)&As[buf][srow][scol] = ra;
        *(bf16x8*)&Bs[buf][srow][scol] = rb;
        __syncthreads();
        if (it < 31) {
            ra = *(const bf16x8*)(Ag + (it + 1) * 32);
            rb = *(const bf16x8*)(Bg + (it + 1) * 32);
        }
        bf16x8 a[4], bfr[2];
        #pragma unroll
        for (int mi = 0; mi < 4; ++mi)
            a[mi] = *(const bf16x8*)&As[buf][wmloc + mi * 16 + lr][lg * 8];
        #pragma unroll
        for (int ni = 0; ni < 2; ++ni)
            bfr[ni] = *(const bf16x8*)&Bs[buf][wnloc + ni * 16 + lr][lg * 8];
        #pragma unroll
        for (int mi = 0; mi < 4; ++mi)
            #pragma unroll
            for (int ni = 0; ni < 2; ++ni)
                acc[mi][ni] = __builtin_amdgcn_mfma_f32_16x16x32_bf16(a[mi], bfr[ni], acc[mi][ni], 0, 0, 0);
    }

    #pragma unroll
    for (int ni = 0; ni < 2; ++ni) {
        const int gc = n0 + wnloc + ni * 16 + lr;
        const float bv = bi[gc];
        #pragma unroll
        for (int mi = 0; mi < 4; ++mi)
            #pragma unroll
            for (int r = 0; r < 4; ++r) {
                const int row = m0 + wmloc + mi * 16 + lg * 4 + r;
                float v = fmaxf(acc[mi][ni][r] + bv, 0.0f);
                C[(size_t)row * NHc + gc] = f2bf(v);
            }
    }
}

// ---------------------------------------------------------------------------
// K2 (fused): scores -> softmax -> att write -> PV -> residual, QB=16 q-rows,
// 512 thr = 8 waves.  R15 structure; P3's V-fragment now read with
// ds_read_b64_tr_b16 (HW transpose) from a [4s][16d]-subtiled V tile:
// 4 tr-reads replace 32 scalar ds_read_u16 per wave per s-tile.
// Single SMEM array so raw byte offsets for the asm are well-defined:
//   Sb   : SMEM[0      .. 16512)  row stride 1032 ush  (33.0 KB)
//   KS   : SMEM[16512  .. 25728)  row stride 72 ush    (P1, 18.4 KB)
//   VS4  : SMEM[16512  .. 24704)  [16 sblk][8 dblk][4][16] subtiles (16 KB)
// Causal: valid iff s < q; row 0 -> uniform 1/1024 (matches jax ref).
// ---------------------------------------------------------------------------
__global__ __launch_bounds__(512, 6)
void attn_fused(const unsigned short* __restrict__ qbuf,
                const unsigned short* __restrict__ kbuf,
                const unsigned short* __restrict__ hidb,
                const float* __restrict__ res,
                float* __restrict__ att, float* __restrict__ outp,
                unsigned short* __restrict__ hidnext)
{
    __shared__ unsigned short SMEM[25728];   // 51456 B

    const int id = blockIdx.x;
    const int kh = id & 7, qt = (id >> 3) & 63, b = id >> 9;
    const int q0 = qt * QB;
    const int t = threadIdx.x, lane = t & 63, w = t >> 6;
    const int lr = lane & 15, lg = lane >> 4;

    bf16x8 aq[2];
    #pragma unroll
    for (int ks = 0; ks < 2; ++ks)
        aq[ks] = *(const bf16x8*)(qbuf + (size_t)(b * Lc + q0 + lr) * NHc + kh * Hc + ks * 32 + lg * 8);

    const int ccount = (q0 + QB + 63) >> 6;   // 64-col chunks needed (1..16)
    const int nchunk2 = (ccount + 1) >> 1;    // 128-col chunks (1..8)

    // ---- P1: scores -> Sb (bf16).  One 128-col K chunk per barrier-pair;
    //      wave w owns the 16-col slice ni == w. ----
    const int krow = t >> 2, kcol = (t & 3) * 16;
    for (int c2 = 0; c2 < nchunk2; ++c2) {
        const unsigned short* kp = kbuf + (size_t)(b * Lc + c2 * 128 + krow) * NHc + kh * Hc + kcol;
        *(bf16x8*)&SMEM[16512 + krow * 72 + kcol]     = *(const bf16x8*)kp;
        *(bf16x8*)&SMEM[16512 + krow * 72 + kcol + 8] = *(const bf16x8*)(kp + 8);
        __syncthreads();
        f32x4 acc = {};
        __builtin_amdgcn_s_setprio(1);
        #pragma unroll
        for (int ks = 0; ks < 2; ++ks) {
            bf16x8 bfr = *(const bf16x8*)&SMEM[16512 + (w * 16 + lr) * 72 + ks * 32 + lg * 8];
            acc = __builtin_amdgcn_mfma_f32_16x16x32_bf16(aq[ks], bfr, acc, 0, 0, 0);
        }
        __builtin_amdgcn_s_setprio(0);
        #pragma unroll
        for (int r = 0; r < 4; ++r)
            SMEM[(lg * 4 + r) * 1032 + c2 * 128 + w * 16 + lr] = f2bf(acc[r] * SCALE);
        __syncthreads();
    }

    // ---- P2: softmax, 2 rows per wave, 3-pass VGPR-lean (R15-proven). ----
    #pragma unroll
    for (int i = 0; i < 2; ++i) {
        const int row = w * 2 + i, qrow = q0 + row;
        float* orow = att + ((size_t)(b * Kc + kh) * Lc + qrow) * Lc;
        if (qrow == 0) {
            const float u = 1.0f / 1024.0f;
            const short ub = (short)f2bf(u);
            bf16x8 pv8;
            #pragma unroll
            for (int j = 0; j < 8; ++j) pv8[j] = ub;
            #pragma unroll
            for (int tt = 0; tt < 2; ++tt) {
                const int col = lane * 8 + tt * 512;
                float4 o = { u, u, u, u };
                *(float4*)(orow + col) = o;
                *(float4*)(orow + col + 4) = o;
                *(bf16x8*)&SMEM[row * 1032 + col] = pv8;
            }
            continue;
        }
        float mx = -3.0e38f;
        #pragma unroll
        for (int tt = 0; tt < 2; ++tt) {
            const int col = lane * 8 + tt * 512;
            bf16x8 v = *(const bf16x8*)&SMEM[row * 1032 + col];
            #pragma unroll
            for (int j = 0; j < 8; ++j)
                if (col + j < qrow) mx = fmaxf(mx, bf2f((unsigned short)v[j]));
        }
        #pragma unroll
        for (int off = 1; off < 64; off <<= 1) mx = fmaxf(mx, __shfl_xor(mx, off));
        float sum = 0.0f;
        #pragma unroll
        for (int tt = 0; tt < 2; ++tt) {
            const int col = lane * 8 + tt * 512;
            bf16x8 v = *(const bf16x8*)&SMEM[row * 1032 + col];
            #pragma unroll
            for (int j = 0; j < 8; ++j)
                sum += (col + j < qrow) ? __expf(bf2f((unsigned short)v[j]) - mx) : 0.0f;
        }
        #pragma unroll
        for (int off = 1; off < 64; off <<= 1) sum += __shfl_xor(sum, off);
        const float inv = 1.0f / sum;
        #pragma unroll
        for (int tt = 0; tt < 2; ++tt) {
            const int col = lane * 8 + tt * 512;
            bf16x8 v = *(const bf16x8*)&SMEM[row * 1032 + col];
            float e[8];
            #pragma unroll
            for (int j = 0; j < 8; ++j)
                e[j] = (col + j < qrow) ? __expf(bf2f((unsigned short)v[j]) - mx) * inv : 0.0f;
            float4 o0 = { e[0], e[1], e[2], e[3] };
            float4 o1 = { e[4], e[5], e[6], e[7] };
            *(float4*)(orow + col) = o0;
            *(float4*)(orow + col + 4) = o1;
            bf16x8 pb;
            #pragma unroll
            for (int j = 0; j < 8; ++j) pb[j] = (short)f2bf(e[j]);
            *(bf16x8*)&SMEM[row * 1032 + col] = pb;
        }
    }
    __syncthreads();

    // ---- P3: PV (+residual).  V staged into [4s][16d] subtiles; B-fragment
    //      read with ds_read_b64_tr_b16: lane (l&15) gets column l&15 of the
    //      group's 128B subtile, elem j = row j (m156/m162 semantics).
    //      Per-lane addr = VS4 + sb(ks,lg)*1024 + w*128 + (l&15)*8 bytes;
    //      offsets 1024 (sb+1), 8192 (ks=1), 9216 (ks=1,sb+1). ----
    const int stiles = (qt == 0) ? 16 : ccount;   // row 0 is a full uniform row
    f32x4 acc3 = {};
    const int dloc = w * 16 + lr, dcol = kh * 128 + dloc;
    const int vs = t >> 3, vdb = t & 7;
    const unsigned vdst = 16512u + (unsigned)((((vs >> 2) * 8 + vdb) * 64) + (vs & 3) * 16);
    const unsigned short* vb = hidb + (size_t)(b * Lc + vs) * Dc + kh * 128 + vdb * 16;
    const unsigned trb = 33024u + (unsigned)(lg * 2048 + w * 128 + lr * 8);
    for (int ti = 0; ti < stiles; ++ti) {
        const unsigned short* vp = vb + (size_t)ti * 64 * Dc;
        *(bf16x8*)&SMEM[vdst]     = *(const bf16x8*)vp;
        *(bf16x8*)&SMEM[vdst + 8] = *(const bf16x8*)(vp + 8);
        __syncthreads();
        __builtin_amdgcn_s_setprio(1);
        bf16x4 t0, t1, t2, t3;
        asm volatile("ds_read_b64_tr_b16 %0, %4\n\t"
                     "ds_read_b64_tr_b16 %1, %4 offset:1024\n\t"
                     "ds_read_b64_tr_b16 %2, %4 offset:8192\n\t"
                     "ds_read_b64_tr_b16 %3, %4 offset:9216"
                     : "=&v"(t0), "=&v"(t1), "=&v"(t2), "=&v"(t3)
                     : "v"(trb));
        bf16x8 pa0 = *(const bf16x8*)&SMEM[lr * 1032 + ti * 64 + lg * 8];
        bf16x8 pa1 = *(const bf16x8*)&SMEM[lr * 1032 + ti * 64 + 32 + lg * 8];
        asm volatile("s_waitcnt lgkmcnt(0)" ::: "memory");
        __builtin_amdgcn_sched_barrier(0);
        bf16x8 bb0, bb1;
        bb0[0] = t0[0]; bb0[1] = t0[1]; bb0[2] = t0[2]; bb0[3] = t0[3];
        bb0[4] = t1[0]; bb0[5] = t1[1]; bb0[6] = t1[2]; bb0[7] = t1[3];
        bb1[0] = t2[0]; bb1[1] = t2[1]; bb1[2] = t2[2]; bb1[3] = t2[3];
        bb1[4] = t3[0]; bb1[5] = t3[1]; bb1[6] = t3[2]; bb1[7] = t3[3];
        acc3 = __builtin_amdgcn_mfma_f32_16x16x32_bf16(pa0, bb0, acc3, 0, 0, 0);
        acc3 = __builtin_amdgcn_mfma_f32_16x16x32_bf16(pa1, bb1, acc3, 0, 0, 0);
        __builtin_amdgcn_s_setprio(0);
        __syncthreads();
    }

    #pragma unroll
    for (int r = 0; r < 4; ++r) {
        const size_t idx = (size_t)(b * Lc + q0 + lg * 4 + r) * Dc + dcol;
        const float v = res[idx] + acc3[r];
        outp[idx] = v;
        if (hidnext) hidnext[idx] = f2bf(v);
    }
}

// ---------------------------------------------------------------------------
extern "C" void kernel_launch(void* const* d_in, const int* in_sizes, int n_in,
                              void* d_out, int out_size, void* d_ws, size_t ws_size,
                              hipStream_t stream)
{
    const float* x  = (const float*)d_in[0];
    const float* Wq = (const float*)d_in[1];
    const float* bq = (const float*)d_in[2];
    const float* Wk = (const float*)d_in[3];
    const float* bk = (const float*)d_in[4];
    float* out = (float*)d_out;

    unsigned short* hidbA = (unsigned short*)d_ws;             // [4096][1024] bf16 (8 MB)
    unsigned short* hidbB = hidbA + (size_t)Bc * Lc * Dc;      // [4096][1024] bf16 (8 MB)
    unsigned short* qb    = hidbB + (size_t)Bc * Lc * Dc;      // [4096][512]  bf16 (4 MB)
    unsigned short* kb    = qb    + (size_t)Bc * Lc * NHc;     // [4096][512]  bf16 (4 MB)

    const int nhid = Bc * Lc * Dc;   // 4194304

    cast_bf16<<<nhid / 8 / 256, 256, 0, stream>>>(x, hidbA, nhid);
    wtrans<<<dim3(16, 8, 4), 256, 0, stream>>>(Wq, Wk, out);

    for (int l = 0; l < 2; ++l) {
        float* attL = out + (size_t)l * (GSZ / 2);
        float* outL = out + GSZ + (size_t)l * OSZ;
        const float* resL = l ? (out + GSZ) : x;
        const unsigned short* hidL = l ? hidbB : hidbA;
        const unsigned short* WtL = (const unsigned short*)attL;

        qk_gemm<<<dim3(32, 4, 2), 512, 0, stream>>>(
            hidL, WtL, WtL + (size_t)NHc * Dc, bq + l * NHc, bk + l * NHc, qb, kb);

        attn_fused<<<Bc * 64 * Kc, 512, 0, stream>>>(
            qb, kb, hidL, resL, attL, outL, l == 0 ? hidbB : (unsigned short*)nullptr);
    }
}

// Round 17
// 187.139 us; speedup vs baseline: 1.1983x; 1.1983x over previous
//
#include <hip/hip_runtime.h>
#include <cstdint>
#include <cstddef>

typedef float  f32x4  __attribute__((ext_vector_type(4)));
typedef short  bf16x8 __attribute__((ext_vector_type(8)));

constexpr int Bc = 4, Lc = 1024, Dc = 1024, Kc = 8, Hc = 64, NHc = 512;
constexpr float SCALE = 0.125f;                       // 1/sqrt(64)
constexpr long long GSZ = 2LL * Bc * Kc * Lc * Lc;    // graphs elems (both layers)
constexpr long long OSZ = (long long)Bc * Lc * Dc;    // hidden elems per layer
constexpr int QB = 16;                                // q-rows per attn block

__device__ __forceinline__ unsigned short f2bf(float f) {
    unsigned u = __float_as_uint(f);
    u += 0x7fffu + ((u >> 16) & 1u);   // RNE
    return (unsigned short)(u >> 16);
}
__device__ __forceinline__ float bf2f(unsigned short s) {
    return __uint_as_float((unsigned)s << 16);
}

// Barrier that waits only on LDS ops (lgkmcnt), NOT on in-flight global
// stores (vmcnt) — avoids __syncthreads()'s full vmcnt(0) drain so att
// writes retire in the background.  sched_barrier stops hoisting (rule #18).
__device__ __forceinline__ void bar_lds() {
    asm volatile("s_waitcnt lgkmcnt(0)" ::: "memory");
    __builtin_amdgcn_s_barrier();
    __builtin_amdgcn_sched_barrier(0);
}

// ---------------------------------------------------------------------------
// cast fp32 -> bf16, 8 elems/thread
// ---------------------------------------------------------------------------
__global__ __launch_bounds__(256)
void cast_bf16(const float* __restrict__ in, unsigned short* __restrict__ outp, int n)
{
    const int i = (blockIdx.x * 256 + threadIdx.x) * 8;
    if (i >= n) return;
    float4 a = *(const float4*)(in + i);
    float4 b = *(const float4*)(in + i + 4);
    bf16x8 v;
    v[0] = (short)f2bf(a.x); v[1] = (short)f2bf(a.y);
    v[2] = (short)f2bf(a.z); v[3] = (short)f2bf(a.w);
    v[4] = (short)f2bf(b.x); v[5] = (short)f2bf(b.y);
    v[6] = (short)f2bf(b.z); v[7] = (short)f2bf(b.w);
    *(bf16x8*)(outp + i) = v;
}

// ---------------------------------------------------------------------------
// K0: W [1024 k][512 n] fp32 -> Wt [512 n][1024 k] bf16, parked in d_out att
// region (overwritten later by attn_fused). z: layer*2 + (0=q,1=k).
// ---------------------------------------------------------------------------
__global__ __launch_bounds__(256)
void wtrans(const float* __restrict__ Wq, const float* __restrict__ Wk,
            float* __restrict__ outbase)
{
    __shared__ float Tl[64][68];
    const int z = blockIdx.z, layer = z >> 1, m = z & 1;
    const float* src = (m ? Wk : Wq) + (size_t)layer * Dc * NHc;
    unsigned short* dst = (unsigned short*)(outbase + (size_t)layer * (GSZ / 2))
                          + (size_t)m * NHc * Dc;
    const int k0 = blockIdx.x * 64, n0 = blockIdx.y * 64;
    const int t = threadIdx.x;
    {
        const int r0 = t >> 4, c0 = (t & 15) * 4;
        #pragma unroll
        for (int i = 0; i < 4; ++i)
            *(float4*)&Tl[r0 + 16 * i][c0] =
                *(const float4*)&src[(size_t)(k0 + r0 + 16 * i) * NHc + n0 + c0];
    }
    __syncthreads();
    {
        const int nn = t >> 2, ks = (t & 3) * 16;
        bf16x8 v0, v1;
        #pragma unroll
        for (int j = 0; j < 8; ++j) v0[j] = (short)f2bf(Tl[ks + j][nn]);
        #pragma unroll
        for (int j = 0; j < 8; ++j) v1[j] = (short)f2bf(Tl[ks + 8 + j][nn]);
        unsigned short* dp = dst + (size_t)(n0 + nn) * Dc + k0 + ks;
        *(bf16x8*)dp       = v0;
        *(bf16x8*)(dp + 8) = v1;
    }
}

// ---------------------------------------------------------------------------
// K1: q/k projection GEMM, LDS-staged (coalesced global reads), double-buffered.
// Tile 128x128, BK=32, 512 thr = 8 waves, wave tile 64x32 (4x2 frags).
// ---------------------------------------------------------------------------
__global__ __launch_bounds__(512)
void qk_gemm(const unsigned short* __restrict__ hidb,
             const unsigned short* __restrict__ Wtq, const unsigned short* __restrict__ Wtk,
             const float* __restrict__ bq, const float* __restrict__ bk,
             unsigned short* __restrict__ qbuf, unsigned short* __restrict__ kbuf)
{
    __shared__ unsigned short As[2][128][40];
    __shared__ unsigned short Bs[2][128][40];

    const unsigned short* Wt = blockIdx.z ? Wtk : Wtq;
    const float* bi = blockIdx.z ? bk : bq;
    unsigned short* C = blockIdx.z ? kbuf : qbuf;
    const int m0 = blockIdx.x * 128, n0 = blockIdx.y * 128;
    const int t = threadIdx.x, lane = t & 63, w = t >> 6;
    const int lr = lane & 15, lg = lane >> 4;
    const int wmloc = (w >> 2) * 64, wnloc = (w & 3) * 32;

    const int srow = t >> 2, scol = (t & 3) * 8;
    const unsigned short* Ag = hidb + (size_t)(m0 + srow) * Dc + scol;
    const unsigned short* Bg = Wt   + (size_t)(n0 + srow) * Dc + scol;

    f32x4 acc[4][2] = {};
    bf16x8 ra = *(const bf16x8*)Ag;
    bf16x8 rb = *(const bf16x8*)Bg;

    for (int it = 0; it < 32; ++it) {
        const int buf = it & 1;
        *(bf16x8*)&As[buf][srow][scol] = ra;
        *(bf16x8*)&Bs[buf][srow][scol] = rb;
        __syncthreads();
        if (it < 31) {
            ra = *(const bf16x8*)(Ag + (it + 1) * 32);
            rb = *(const bf16x8*)(Bg + (it + 1) * 32);
        }
        bf16x8 a[4], bfr[2];
        #pragma unroll
        for (int mi = 0; mi < 4; ++mi)
            a[mi] = *(const bf16x8*)&As[buf][wmloc + mi * 16 + lr][lg * 8];
        #pragma unroll
        for (int ni = 0; ni < 2; ++ni)
            bfr[ni] = *(const bf16x8*)&Bs[buf][wnloc + ni * 16 + lr][lg * 8];
        #pragma unroll
        for (int mi = 0; mi < 4; ++mi)
            #pragma unroll
            for (int ni = 0; ni < 2; ++ni)
                acc[mi][ni] = __builtin_amdgcn_mfma_f32_16x16x32_bf16(a[mi], bfr[ni], acc[mi][ni], 0, 0, 0);
    }

    #pragma unroll
    for (int ni = 0; ni < 2; ++ni) {
        const int gc = n0 + wnloc + ni * 16 + lr;
        const float bv = bi[gc];
        #pragma unroll
        for (int mi = 0; mi < 4; ++mi)
            #pragma unroll
            for (int r = 0; r < 4; ++r) {
                const int row = m0 + wmloc + mi * 16 + lg * 4 + r;
                float v = fmaxf(acc[mi][ni][r] + bv, 0.0f);
                C[(size_t)row * NHc + gc] = f2bf(v);
            }
    }
}

// ---------------------------------------------------------------------------
// K2 (fused): scores -> softmax -> att write -> PV -> residual, QB=16 q-rows,
// 512 thr = 8 waves.  R15 structure plus:
//  (a) lgkmcnt-only barriers (bar_lds) — att global stores no longer drained
//      at every barrier (removes the vmcnt(0) store-drain stall);
//  (b) LPT block order: heavy qt families (63,62,... and qt=0) start first.
// LDS 50.3 KB; 3-pass VGPR-lean softmax; launch_bounds(512,6).
// Causal: valid iff s < q; row 0 -> uniform 1/1024 (matches jax ref).
// ---------------------------------------------------------------------------
__global__ __launch_bounds__(512, 6)
void attn_fused(const unsigned short* __restrict__ qbuf,
                const unsigned short* __restrict__ kbuf,
                const unsigned short* __restrict__ hidb,
                const float* __restrict__ res,
                float* __restrict__ att, float* __restrict__ outp,
                unsigned short* __restrict__ hidnext)
{
    __shared__ unsigned short Sb[QB][1032];     // bf16 score/P strip (33.0 KB)
    union KVU {
        unsigned short KS[128][72];             // K chunk: 128 s-rows x 64 h (18.4 KB)
        unsigned short VS[64][136];             // V tile: 64 s-rows x 128 d  (17.4 KB)
    };
    __shared__ KVU kv;

    const int id = blockIdx.x;
    const int kh = id & 7, slot = (id >> 3) & 63, b = id >> 9;
    const int qt = (slot == 0) ? 0 : 64 - slot;   // LPT: heavy blocks first
    const int q0 = qt * QB;
    const int t = threadIdx.x, lane = t & 63, w = t >> 6;
    const int lr = lane & 15, lg = lane >> 4;

    bf16x8 aq[2];
    #pragma unroll
    for (int ks = 0; ks < 2; ++ks)
        aq[ks] = *(const bf16x8*)(qbuf + (size_t)(b * Lc + q0 + lr) * NHc + kh * Hc + ks * 32 + lg * 8);

    const int ccount = (q0 + QB + 63) >> 6;   // 64-col chunks needed (1..16)
    const int nchunk2 = (ccount + 1) >> 1;    // 128-col chunks (1..8)

    // ---- P1: scores -> Sb (bf16).  One 128-col K chunk per barrier-pair;
    //      wave w owns the 16-col slice ni == w. ----
    const int krow = t >> 2, kcol = (t & 3) * 16;
    for (int c2 = 0; c2 < nchunk2; ++c2) {
        const unsigned short* kp = kbuf + (size_t)(b * Lc + c2 * 128 + krow) * NHc + kh * Hc + kcol;
        *(bf16x8*)&kv.KS[krow][kcol]     = *(const bf16x8*)kp;
        *(bf16x8*)&kv.KS[krow][kcol + 8] = *(const bf16x8*)(kp + 8);
        bar_lds();
        f32x4 acc = {};
        __builtin_amdgcn_s_setprio(1);
        #pragma unroll
        for (int ks = 0; ks < 2; ++ks) {
            bf16x8 bfr = *(const bf16x8*)&kv.KS[w * 16 + lr][ks * 32 + lg * 8];
            acc = __builtin_amdgcn_mfma_f32_16x16x32_bf16(aq[ks], bfr, acc, 0, 0, 0);
        }
        __builtin_amdgcn_s_setprio(0);
        #pragma unroll
        for (int r = 0; r < 4; ++r)
            Sb[lg * 4 + r][c2 * 128 + w * 16 + lr] = f2bf(acc[r] * SCALE);
        bar_lds();
    }

    // ---- P2: softmax, 2 rows per wave, 3-pass VGPR-lean (R15-proven).
    //      fp32 att stores are left in flight (no vmcnt drain). ----
    #pragma unroll
    for (int i = 0; i < 2; ++i) {
        const int row = w * 2 + i, qrow = q0 + row;
        float* orow = att + ((size_t)(b * Kc + kh) * Lc + qrow) * Lc;
        if (qrow == 0) {
            const float u = 1.0f / 1024.0f;
            const short ub = (short)f2bf(u);
            bf16x8 pv8;
            #pragma unroll
            for (int j = 0; j < 8; ++j) pv8[j] = ub;
            #pragma unroll
            for (int tt = 0; tt < 2; ++tt) {
                const int col = lane * 8 + tt * 512;
                float4 o = { u, u, u, u };
                *(float4*)(orow + col) = o;
                *(float4*)(orow + col + 4) = o;
                *(bf16x8*)&Sb[row][col] = pv8;
            }
            continue;
        }
        float mx = -3.0e38f;
        #pragma unroll
        for (int tt = 0; tt < 2; ++tt) {
            const int col = lane * 8 + tt * 512;
            bf16x8 v = *(const bf16x8*)&Sb[row][col];
            #pragma unroll
            for (int j = 0; j < 8; ++j)
                if (col + j < qrow) mx = fmaxf(mx, bf2f((unsigned short)v[j]));
        }
        #pragma unroll
        for (int off = 1; off < 64; off <<= 1) mx = fmaxf(mx, __shfl_xor(mx, off));
        float sum = 0.0f;
        #pragma unroll
        for (int tt = 0; tt < 2; ++tt) {
            const int col = lane * 8 + tt * 512;
            bf16x8 v = *(const bf16x8*)&Sb[row][col];
            #pragma unroll
            for (int j = 0; j < 8; ++j)
                sum += (col + j < qrow) ? __expf(bf2f((unsigned short)v[j]) - mx) : 0.0f;
        }
        #pragma unroll
        for (int off = 1; off < 64; off <<= 1) sum += __shfl_xor(sum, off);
        const float inv = 1.0f / sum;
        #pragma unroll
        for (int tt = 0; tt < 2; ++tt) {
            const int col = lane * 8 + tt * 512;
            bf16x8 v = *(const bf16x8*)&Sb[row][col];
            float e[8];
            #pragma unroll
            for (int j = 0; j < 8; ++j)
                e[j] = (col + j < qrow) ? __expf(bf2f((unsigned short)v[j]) - mx) * inv : 0.0f;
            float4 o0 = { e[0], e[1], e[2], e[3] };
            float4 o1 = { e[4], e[5], e[6], e[7] };
            *(float4*)(orow + col) = o0;
            *(float4*)(orow + col + 4) = o1;
            bf16x8 pb;
            #pragma unroll
            for (int j = 0; j < 8; ++j) pb[j] = (short)f2bf(e[j]);
            *(bf16x8*)&Sb[row][col] = pb;
        }
    }
    bar_lds();

    // ---- P3: PV (+residual).  Single V tile, 2 lgkm-barriers per tile;
    //      staging coalesced; fragments gathered from LDS (R9-proven). ----
    const int stiles = (qt == 0) ? 16 : ccount;   // row 0 is a full uniform row
    f32x4 acc3 = {};
    const int dloc = w * 16 + lr, dcol = kh * 128 + dloc;
    const int vrow = t >> 3, vcol = (t & 7) * 8;
    const unsigned short* vb = hidb + (size_t)(b * Lc + vrow) * Dc + kh * 128 + vcol;
    for (int ti = 0; ti < stiles; ++ti) {
        const unsigned short* vp = vb + (size_t)ti * 64 * Dc;
        *(bf16x8*)&kv.VS[vrow][vcol]      = *(const bf16x8*)vp;
        *(bf16x8*)&kv.VS[vrow][vcol + 64] = *(const bf16x8*)(vp + 64);
        bar_lds();
        __builtin_amdgcn_s_setprio(1);
        #pragma unroll
        for (int ks = 0; ks < 2; ++ks) {
            bf16x8 pa = *(const bf16x8*)&Sb[lr][ti * 64 + ks * 32 + lg * 8];
            bf16x8 bb;
            #pragma unroll
            for (int j = 0; j < 8; ++j)
                bb[j] = (short)kv.VS[ks * 32 + lg * 8 + j][dloc];
            acc3 = __builtin_amdgcn_mfma_f32_16x16x32_bf16(pa, bb, acc3, 0, 0, 0);
        }
        __builtin_amdgcn_s_setprio(0);
        bar_lds();
    }

    #pragma unroll
    for (int r = 0; r < 4; ++r) {
        const size_t idx = (size_t)(b * Lc + q0 + lg * 4 + r) * Dc + dcol;
        const float v = res[idx] + acc3[r];
        outp[idx] = v;
        if (hidnext) hidnext[idx] = f2bf(v);
    }
}

// ---------------------------------------------------------------------------
extern "C" void kernel_launch(void* const* d_in, const int* in_sizes, int n_in,
                              void* d_out, int out_size, void* d_ws, size_t ws_size,
                              hipStream_t stream)
{
    const float* x  = (const float*)d_in[0];
    const float* Wq = (const float*)d_in[1];
    const float* bq = (const float*)d_in[2];
    const float* Wk = (const float*)d_in[3];
    const float* bk = (const float*)d_in[4];
    float* out = (float*)d_out;

    unsigned short* hidbA = (unsigned short*)d_ws;             // [4096][1024] bf16 (8 MB)
    unsigned short* hidbB = hidbA + (size_t)Bc * Lc * Dc;      // [4096][1024] bf16 (8 MB)
    unsigned short* qb    = hidbB + (size_t)Bc * Lc * Dc;      // [4096][512]  bf16 (4 MB)
    unsigned short* kb    = qb    + (size_t)Bc * Lc * NHc;     // [4096][512]  bf16 (4 MB)

    const int nhid = Bc * Lc * Dc;   // 4194304

    cast_bf16<<<nhid / 8 / 256, 256, 0, stream>>>(x, hidbA, nhid);
    wtrans<<<dim3(16, 8, 4), 256, 0, stream>>>(Wq, Wk, out);

    for (int l = 0; l < 2; ++l) {
        float* attL = out + (size_t)l * (GSZ / 2);
        float* outL = out + GSZ + (size_t)l * OSZ;
        const float* resL = l ? (out + GSZ) : x;
        const unsigned short* hidL = l ? hidbB : hidbA;
        const unsigned short* WtL = (const unsigned short*)attL;

        qk_gemm<<<dim3(32, 4, 2), 512, 0, stream>>>(
            hidL, WtL, WtL + (size_t)NHc * Dc, bq + l * NHc, bk + l * NHc, qb, kb);

        attn_fused<<<Bc * 64 * Kc, 512, 0, stream>>>(
            qb, kb, hidL, resL, attL, outL, l == 0 ? hidbB : (unsigned short*)nullptr);
    }
}

// Round 18
// 186.596 us; speedup vs baseline: 1.2018x; 1.0029x over previous
//
#include <hip/hip_runtime.h>
#include <cstdint>
#include <cstddef>

typedef float  f32x4  __attribute__((ext_vector_type(4)));
typedef short  bf16x8 __attribute__((ext_vector_type(8)));
typedef unsigned int u32;
typedef __attribute__((address_space(1))) const u32 gu32;
typedef __attribute__((address_space(3))) u32 su32;

constexpr int Bc = 4, Lc = 1024, Dc = 1024, Kc = 8, Hc = 64, NHc = 512;
constexpr float SCALE = 0.125f;                       // 1/sqrt(64)
constexpr long long GSZ = 2LL * Bc * Kc * Lc * Lc;    // graphs elems (both layers)
constexpr long long OSZ = (long long)Bc * Lc * Dc;    // hidden elems per layer
constexpr int QB = 16;                                // q-rows per attn block

__device__ __forceinline__ unsigned short f2bf(float f) {
    unsigned u = __float_as_uint(f);
    u += 0x7fffu + ((u >> 16) & 1u);   // RNE
    return (unsigned short)(u >> 16);
}
__device__ __forceinline__ float bf2f(unsigned short s) {
    return __uint_as_float((unsigned)s << 16);
}

// Barrier that waits only on LDS ops (lgkmcnt), NOT in-flight global stores.
__device__ __forceinline__ void bar_lds() {
    asm volatile("s_waitcnt lgkmcnt(0)" ::: "memory");
    __builtin_amdgcn_s_barrier();
    __builtin_amdgcn_sched_barrier(0);
}

// ---------------------------------------------------------------------------
// cast fp32 -> bf16, 8 elems/thread
// ---------------------------------------------------------------------------
__global__ __launch_bounds__(256)
void cast_bf16(const float* __restrict__ in, unsigned short* __restrict__ outp, int n)
{
    const int i = (blockIdx.x * 256 + threadIdx.x) * 8;
    if (i >= n) return;
    float4 a = *(const float4*)(in + i);
    float4 b = *(const float4*)(in + i + 4);
    bf16x8 v;
    v[0] = (short)f2bf(a.x); v[1] = (short)f2bf(a.y);
    v[2] = (short)f2bf(a.z); v[3] = (short)f2bf(a.w);
    v[4] = (short)f2bf(b.x); v[5] = (short)f2bf(b.y);
    v[6] = (short)f2bf(b.z); v[7] = (short)f2bf(b.w);
    *(bf16x8*)(outp + i) = v;
}

// ---------------------------------------------------------------------------
// K0: W [1024 k][512 n] fp32 -> Wt [512 n][1024 k] bf16, parked in d_out att
// region (overwritten later by attn_fused). z: layer*2 + (0=q,1=k).
// ---------------------------------------------------------------------------
__global__ __launch_bounds__(256)
void wtrans(const float* __restrict__ Wq, const float* __restrict__ Wk,
            float* __restrict__ outbase)
{
    __shared__ float Tl[64][68];
    const int z = blockIdx.z, layer = z >> 1, m = z & 1;
    const float* src = (m ? Wk : Wq) + (size_t)layer * Dc * NHc;
    unsigned short* dst = (unsigned short*)(outbase + (size_t)layer * (GSZ / 2))
                          + (size_t)m * NHc * Dc;
    const int k0 = blockIdx.x * 64, n0 = blockIdx.y * 64;
    const int t = threadIdx.x;
    {
        const int r0 = t >> 4, c0 = (t & 15) * 4;
        #pragma unroll
        for (int i = 0; i < 4; ++i)
            *(float4*)&Tl[r0 + 16 * i][c0] =
                *(const float4*)&src[(size_t)(k0 + r0 + 16 * i) * NHc + n0 + c0];
    }
    __syncthreads();
    {
        const int nn = t >> 2, ks = (t & 3) * 16;
        bf16x8 v0, v1;
        #pragma unroll
        for (int j = 0; j < 8; ++j) v0[j] = (short)f2bf(Tl[ks + j][nn]);
        #pragma unroll
        for (int j = 0; j < 8; ++j) v1[j] = (short)f2bf(Tl[ks + 8 + j][nn]);
        unsigned short* dp = dst + (size_t)(n0 + nn) * Dc + k0 + ks;
        *(bf16x8*)dp       = v0;
        *(bf16x8*)(dp + 8) = v1;
    }
}

// ---------------------------------------------------------------------------
// K1: q/k projection GEMM.  global_load_lds width=16 (m97 ladder step) with
// both-sides XOR swizzle (rule #21): linear LDS [128][32], write-side slot
// permutation folded into per-lane GLOBAL address, read-side slot = lg ^
// ((lr>>1)&3) -> all 8 bank-slots x2 lanes = conflict-free.  One barrier per
// K-step; __syncthreads' vmcnt(0) drain is the async-load completion wait.
// ---------------------------------------------------------------------------
__global__ __launch_bounds__(512)
void qk_gemm(const unsigned short* __restrict__ hidb,
             const unsigned short* __restrict__ Wtq, const unsigned short* __restrict__ Wtk,
             const float* __restrict__ bq, const float* __restrict__ bk,
             unsigned short* __restrict__ qbuf, unsigned short* __restrict__ kbuf)
{
    __shared__ unsigned short As[2][128][32];
    __shared__ unsigned short Bs[2][128][32];

    const unsigned short* Wt = blockIdx.z ? Wtk : Wtq;
    const float* bi = blockIdx.z ? bk : bq;
    unsigned short* C = blockIdx.z ? kbuf : qbuf;
    const int m0 = blockIdx.x * 128, n0 = blockIdx.y * 128;
    const int t = threadIdx.x, lane = t & 63, w = t >> 6;
    const int lr = lane & 15, lg = lane >> 4;
    const int wmloc = (w >> 2) * 64, wnloc = (w & 3) * 32;

    // staging: wave w covers rows w*16..w*16+15; lane l -> row w*16+(l>>2),
    // LDS 16B-slot (l&3); global slot XOR-permuted so LDS(r,s) = G(r, s^((r>>1)&3)).
    const int arow = w * 16 + (lane >> 2);
    const int aslot = (lane & 3) ^ ((lane >> 3) & 3);   // == (l&3)^((arow>>1)&3)
    const unsigned short* Ag = hidb + (size_t)(m0 + arow) * Dc + aslot * 8;
    const unsigned short* Bg = Wt   + (size_t)(n0 + arow) * Dc + aslot * 8;

    f32x4 acc[4][2] = {};
    const int slr = lg ^ ((lr >> 1) & 3);   // read-side slot (row-parity XOR)

    // prologue: issue tile 0 into buf 0 (wave-uniform LDS base; HW adds lane*16)
    __builtin_amdgcn_global_load_lds((const gu32*)Ag, (su32*)&As[0][w * 16][0], 16, 0, 0);
    __builtin_amdgcn_global_load_lds((const gu32*)Bg, (su32*)&Bs[0][w * 16][0], 16, 0, 0);

    for (int it = 0; it < 32; ++it) {
        const int buf = it & 1;
        __syncthreads();   // vmcnt(0): loads for buf landed; prev reads done
        if (it < 31) {
            const int koff = (it + 1) * 32;
            __builtin_amdgcn_global_load_lds((const gu32*)(Ag + koff),
                                             (su32*)&As[buf ^ 1][w * 16][0], 16, 0, 0);
            __builtin_amdgcn_global_load_lds((const gu32*)(Bg + koff),
                                             (su32*)&Bs[buf ^ 1][w * 16][0], 16, 0, 0);
        }
        bf16x8 a[4], bfr[2];
        #pragma unroll
        for (int mi = 0; mi < 4; ++mi)
            a[mi] = *(const bf16x8*)&As[buf][wmloc + mi * 16 + lr][slr * 8];
        #pragma unroll
        for (int ni = 0; ni < 2; ++ni)
            bfr[ni] = *(const bf16x8*)&Bs[buf][wnloc + ni * 16 + lr][slr * 8];
        #pragma unroll
        for (int mi = 0; mi < 4; ++mi)
            #pragma unroll
            for (int ni = 0; ni < 2; ++ni)
                acc[mi][ni] = __builtin_amdgcn_mfma_f32_16x16x32_bf16(a[mi], bfr[ni], acc[mi][ni], 0, 0, 0);
    }

    #pragma unroll
    for (int ni = 0; ni < 2; ++ni) {
        const int gc = n0 + wnloc + ni * 16 + lr;
        const float bv = bi[gc];
        #pragma unroll
        for (int mi = 0; mi < 4; ++mi)
            #pragma unroll
            for (int r = 0; r < 4; ++r) {
                const int row = m0 + wmloc + mi * 16 + lg * 4 + r;
                float v = fmaxf(acc[mi][ni][r] + bv, 0.0f);
                C[(size_t)row * NHc + gc] = f2bf(v);
            }
    }
}

// ---------------------------------------------------------------------------
// K2 (fused): scores -> softmax -> att write -> PV -> residual, QB=16 q-rows,
// 512 thr = 8 waves.  R17 winner: lgkm-only barriers (att stores drain in
// background), LPT block order, 50.3 KB LDS, 3-pass VGPR-lean softmax.
// Causal: valid iff s < q; row 0 -> uniform 1/1024 (matches jax ref).
// ---------------------------------------------------------------------------
__global__ __launch_bounds__(512, 6)
void attn_fused(const unsigned short* __restrict__ qbuf,
                const unsigned short* __restrict__ kbuf,
                const unsigned short* __restrict__ hidb,
                const float* __restrict__ res,
                float* __restrict__ att, float* __restrict__ outp,
                unsigned short* __restrict__ hidnext)
{
    __shared__ unsigned short Sb[QB][1032];     // bf16 score/P strip (33.0 KB)
    union KVU {
        unsigned short KS[128][72];             // K chunk: 128 s-rows x 64 h (18.4 KB)
        unsigned short VS[64][136];             // V tile: 64 s-rows x 128 d  (17.4 KB)
    };
    __shared__ KVU kv;

    const int id = blockIdx.x;
    const int kh = id & 7, slot = (id >> 3) & 63, b = id >> 9;
    const int qt = (slot == 0) ? 0 : 64 - slot;   // LPT: heavy blocks first
    const int q0 = qt * QB;
    const int t = threadIdx.x, lane = t & 63, w = t >> 6;
    const int lr = lane & 15, lg = lane >> 4;

    bf16x8 aq[2];
    #pragma unroll
    for (int ks = 0; ks < 2; ++ks)
        aq[ks] = *(const bf16x8*)(qbuf + (size_t)(b * Lc + q0 + lr) * NHc + kh * Hc + ks * 32 + lg * 8);

    const int ccount = (q0 + QB + 63) >> 6;   // 64-col chunks needed (1..16)
    const int nchunk2 = (ccount + 1) >> 1;    // 128-col chunks (1..8)

    // ---- P1: scores -> Sb (bf16).  One 128-col K chunk per barrier-pair;
    //      wave w owns the 16-col slice ni == w. ----
    const int krow = t >> 2, kcol = (t & 3) * 16;
    for (int c2 = 0; c2 < nchunk2; ++c2) {
        const unsigned short* kp = kbuf + (size_t)(b * Lc + c2 * 128 + krow) * NHc + kh * Hc + kcol;
        *(bf16x8*)&kv.KS[krow][kcol]     = *(const bf16x8*)kp;
        *(bf16x8*)&kv.KS[krow][kcol + 8] = *(const bf16x8*)(kp + 8);
        bar_lds();
        f32x4 acc = {};
        __builtin_amdgcn_s_setprio(1);
        #pragma unroll
        for (int ks = 0; ks < 2; ++ks) {
            bf16x8 bfr = *(const bf16x8*)&kv.KS[w * 16 + lr][ks * 32 + lg * 8];
            acc = __builtin_amdgcn_mfma_f32_16x16x32_bf16(aq[ks], bfr, acc, 0, 0, 0);
        }
        __builtin_amdgcn_s_setprio(0);
        #pragma unroll
        for (int r = 0; r < 4; ++r)
            Sb[lg * 4 + r][c2 * 128 + w * 16 + lr] = f2bf(acc[r] * SCALE);
        bar_lds();
    }

    // ---- P2: softmax, 2 rows per wave, 3-pass VGPR-lean.  att stores are
    //      left in flight (no vmcnt drain). ----
    #pragma unroll
    for (int i = 0; i < 2; ++i) {
        const int row = w * 2 + i, qrow = q0 + row;
        float* orow = att + ((size_t)(b * Kc + kh) * Lc + qrow) * Lc;
        if (qrow == 0) {
            const float u = 1.0f / 1024.0f;
            const short ub = (short)f2bf(u);
            bf16x8 pv8;
            #pragma unroll
            for (int j = 0; j < 8; ++j) pv8[j] = ub;
            #pragma unroll
            for (int tt = 0; tt < 2; ++tt) {
                const int col = lane * 8 + tt * 512;
                float4 o = { u, u, u, u };
                *(float4*)(orow + col) = o;
                *(float4*)(orow + col + 4) = o;
                *(bf16x8*)&Sb[row][col] = pv8;
            }
            continue;
        }
        float mx = -3.0e38f;
        #pragma unroll
        for (int tt = 0; tt < 2; ++tt) {
            const int col = lane * 8 + tt * 512;
            bf16x8 v = *(const bf16x8*)&Sb[row][col];
            #pragma unroll
            for (int j = 0; j < 8; ++j)
                if (col + j < qrow) mx = fmaxf(mx, bf2f((unsigned short)v[j]));
        }
        #pragma unroll
        for (int off = 1; off < 64; off <<= 1) mx = fmaxf(mx, __shfl_xor(mx, off));
        float sum = 0.0f;
        #pragma unroll
        for (int tt = 0; tt < 2; ++tt) {
            const int col = lane * 8 + tt * 512;
            bf16x8 v = *(const bf16x8*)&Sb[row][col];
            #pragma unroll
            for (int j = 0; j < 8; ++j)
                sum += (col + j < qrow) ? __expf(bf2f((unsigned short)v[j]) - mx) : 0.0f;
        }
        #pragma unroll
        for (int off = 1; off < 64; off <<= 1) sum += __shfl_xor(sum, off);
        const float inv = 1.0f / sum;
        #pragma unroll
        for (int tt = 0; tt < 2; ++tt) {
            const int col = lane * 8 + tt * 512;
            bf16x8 v = *(const bf16x8*)&Sb[row][col];
            float e[8];
            #pragma unroll
            for (int j = 0; j < 8; ++j)
                e[j] = (col + j < qrow) ? __expf(bf2f((unsigned short)v[j]) - mx) * inv : 0.0f;
            float4 o0 = { e[0], e[1], e[2], e[3] };
            float4 o1 = { e[4], e[5], e[6], e[7] };
            *(float4*)(orow + col) = o0;
            *(float4*)(orow + col + 4) = o1;
            bf16x8 pb;
            #pragma unroll
            for (int j = 0; j < 8; ++j) pb[j] = (short)f2bf(e[j]);
            *(bf16x8*)&Sb[row][col] = pb;
        }
    }
    bar_lds();

    // ---- P3: PV (+residual).  Single V tile, 2 lgkm-barriers per tile;
    //      staging coalesced; fragments gathered from LDS (R9-proven). ----
    const int stiles = (qt == 0) ? 16 : ccount;   // row 0 is a full uniform row
    f32x4 acc3 = {};
    const int dloc = w * 16 + lr, dcol = kh * 128 + dloc;
    const int vrow = t >> 3, vcol = (t & 7) * 8;
    const unsigned short* vb = hidb + (size_t)(b * Lc + vrow) * Dc + kh * 128 + vcol;
    for (int ti = 0; ti < stiles; ++ti) {
        const unsigned short* vp = vb + (size_t)ti * 64 * Dc;
        *(bf16x8*)&kv.VS[vrow][vcol]      = *(const bf16x8*)vp;
        *(bf16x8*)&kv.VS[vrow][vcol + 64] = *(const bf16x8*)(vp + 64);
        bar_lds();
        __builtin_amdgcn_s_setprio(1);
        #pragma unroll
        for (int ks = 0; ks < 2; ++ks) {
            bf16x8 pa = *(const bf16x8*)&Sb[lr][ti * 64 + ks * 32 + lg * 8];
            bf16x8 bb;
            #pragma unroll
            for (int j = 0; j < 8; ++j)
                bb[j] = (short)kv.VS[ks * 32 + lg * 8 + j][dloc];
            acc3 = __builtin_amdgcn_mfma_f32_16x16x32_bf16(pa, bb, acc3, 0, 0, 0);
        }
        __builtin_amdgcn_s_setprio(0);
        bar_lds();
    }

    #pragma unroll
    for (int r = 0; r < 4; ++r) {
        const size_t idx = (size_t)(b * Lc + q0 + lg * 4 + r) * Dc + dcol;
        const float v = res[idx] + acc3[r];
        outp[idx] = v;
        if (hidnext) hidnext[idx] = f2bf(v);
    }
}

// ---------------------------------------------------------------------------
extern "C" void kernel_launch(void* const* d_in, const int* in_sizes, int n_in,
                              void* d_out, int out_size, void* d_ws, size_t ws_size,
                              hipStream_t stream)
{
    const float* x  = (const float*)d_in[0];
    const float* Wq = (const float*)d_in[1];
    const float* bq = (const float*)d_in[2];
    const float* Wk = (const float*)d_in[3];
    const float* bk = (const float*)d_in[4];
    float* out = (float*)d_out;

    unsigned short* hidbA = (unsigned short*)d_ws;             // [4096][1024] bf16 (8 MB)
    unsigned short* hidbB = hidbA + (size_t)Bc * Lc * Dc;      // [4096][1024] bf16 (8 MB)
    unsigned short* qb    = hidbB + (size_t)Bc * Lc * Dc;      // [4096][512]  bf16 (4 MB)
    unsigned short* kb    = qb    + (size_t)Bc * Lc * NHc;     // [4096][512]  bf16 (4 MB)

    const int nhid = Bc * Lc * Dc;   // 4194304

    cast_bf16<<<nhid / 8 / 256, 256, 0, stream>>>(x, hidbA, nhid);
    wtrans<<<dim3(16, 8, 4), 256, 0, stream>>>(Wq, Wk, out);

    for (int l = 0; l < 2; ++l) {
        float* attL = out + (size_t)l * (GSZ / 2);
        float* outL = out + GSZ + (size_t)l * OSZ;
        const float* resL = l ? (out + GSZ) : x;
        const unsigned short* hidL = l ? hidbB : hidbA;
        const unsigned short* WtL = (const unsigned short*)attL;

        qk_gemm<<<dim3(32, 4, 2), 512, 0, stream>>>(
            hidL, WtL, WtL + (size_t)NHc * Dc, bq + l * NHc, bk + l * NHc, qb, kb);

        attn_fused<<<Bc * 64 * Kc, 512, 0, stream>>>(
            qb, kb, hidL, resL, attL, outL, l == 0 ? hidbB : (unsigned short*)nullptr);
    }
}